// Round 10
// baseline (176.931 us; speedup 1.0000x reference)
//
#include <hip/hip_runtime.h>
#include <hip/hip_bf16.h>
#include <stdint.h>

// B=2048, D=1024, H=8, DH=64, INNER=512; attention over flattened (B*H)=16384 axis.
// fp32 in/out. Pipeline:
//   prep_all: x->xb bf16; weights -> transposed bf16
//   GEMM-1: xb @ WtQKV^T -> QK (Q pre-scaled) + Vt (V transposed)
//   flash attention r24: r19 staging/dbuf/1-barrier structure, MFMA shape
//     16x16x32 -> 32x32x16 (half the MFMA instructions for the same FLOPs,
//     matrix cycles -17%, PV V-frag ds_reads halved). S^T = K·Q^T per
//     (32-key ts, 32-qrow sq) unit; NEW sigma sig(p)=p^12 iff ((p>>2)&3) in {1,2}
//     makes S regs [8t..8t+7] == PV B-operand slots (k=(lane>>5)*8+j) directly.
//     C/D layout col=lane&31, row=(reg&3)+8*(reg>>2)+4*(lane>>5) [m74/m101].
//     4 units keep the QK(i+1) || SM+PV(i) interleave.
//   merge -> GEMM-2: Ob @ WtOut^T + bias -> fp32 out.
// ws: QK 4M | Vt 2M | Ob 2M | xb 4M | WtQKV 3M | WtOut 1M | accP ns*4M | lP ns*64K.

typedef __bf16 bf16_t;
typedef __bf16 bf16x4 __attribute__((ext_vector_type(4)));
typedef __bf16 bf16x8 __attribute__((ext_vector_type(8)));
typedef float floatx4 __attribute__((ext_vector_type(4)));
typedef float floatx16 __attribute__((ext_vector_type(16)));

#define F16_ZERO (floatx16){0.f,0.f,0.f,0.f,0.f,0.f,0.f,0.f,0.f,0.f,0.f,0.f,0.f,0.f,0.f,0.f}

__device__ __forceinline__ floatx4 mfma16(bf16x8 a, bf16x8 b, floatx4 c) {
    return __builtin_amdgcn_mfma_f32_16x16x32_bf16(a, b, c, 0, 0, 0);
}

__device__ __forceinline__ floatx16 mfma32(bf16x8 a, bf16x8 b, floatx16 c) {
    return __builtin_amdgcn_mfma_f32_32x32x16_bf16(a, b, c, 0, 0, 0);
}

__device__ __forceinline__ bf16x8 cvt8(float4 a, float4 b) {
    bf16x8 o;
    o[0] = (bf16_t)a.x; o[1] = (bf16_t)a.y; o[2] = (bf16_t)a.z; o[3] = (bf16_t)a.w;
    o[4] = (bf16_t)b.x; o[5] = (bf16_t)b.y; o[6] = (bf16_t)b.z; o[7] = (bf16_t)b.w;
    return o;
}

// ---------------- fused prep (r14, unchanged) ----------------
__device__ __forceinline__ void transpose_body(const float* __restrict__ in, int N,
                                               bf16_t* __restrict__ out, int ldo,
                                               int bx, int by, int tid, float (*tile)[33]) {
    int n0 = bx * 32, k0 = by * 32;
    int tx = tid & 31, ty = tid >> 5;
#pragma unroll
    for (int i = 0; i < 32; i += 8)
        tile[ty + i][tx] = in[(size_t)(k0 + ty + i) * N + (n0 + tx)];
    __syncthreads();
#pragma unroll
    for (int i = 0; i < 32; i += 8)
        out[(size_t)(n0 + ty + i) * ldo + (k0 + tx)] = (bf16_t)tile[tx][ty + i];
}

__global__ __launch_bounds__(256) void prep_all(const float* __restrict__ x,
                                                bf16_t* __restrict__ xb,
                                                const float* __restrict__ Wq,
                                                const float* __restrict__ Wkv,
                                                const float* __restrict__ Wout,
                                                bf16_t* __restrict__ WtQKV,
                                                bf16_t* __restrict__ WtOut) {
    __shared__ float tile[32][33];
    int b = blockIdx.x, tid = threadIdx.x;
    if (b < 1024) {
        int i = (b * 256 + tid) * 8;
        *(bf16x8*)(xb + i) = cvt8(*(const float4*)(x + i), *(const float4*)(x + i + 4));
    } else if (b < 1536) {
        b -= 1024;
        transpose_body(Wq, 512, WtQKV, 1024, b & 15, b >> 4, tid, tile);
    } else if (b < 2560) {
        b -= 1536;
        transpose_body(Wkv, 1024, WtQKV + 512 * 1024, 1024, b & 31, b >> 5, tid, tile);
    } else {
        b -= 2560;
        transpose_body(Wout, 1024, WtOut, 512, b & 31, b >> 5, tid, tile);
    }
}

// ---------------- GEMM (r13/r14-proven, unchanged) ----------------
template <int OF32, int MI>
__global__ __launch_bounds__(256) void gemm_bt(const bf16_t* __restrict__ A,
                                               const bf16_t* __restrict__ Bt,
                                               const float* __restrict__ bias,
                                               void* __restrict__ Cout,
                                               bf16_t* __restrict__ VtOut, int vt_col0,
                                               int K, int lda, int ldb, int ldc,
                                               float qscale, int qcols) {
    constexpr int MT = MI * 32;
    constexpr int PA = MT / 64;
    __shared__ bf16_t sA[MT * 64];
    __shared__ bf16_t sB[64 * 64];
    int tid = threadIdx.x;
    int wave = tid >> 6, lane = tid & 63;
    int lm = lane & 15, q = lane >> 4;
    int bm = blockIdx.x * MT, bn = blockIdx.y * 64;
    int wm = (wave >> 1) * (MT / 2), wn = (wave & 1) * 32;

    int c0 = (tid & 3) * 2, c1 = c0 + 1;
    int rA[PA], swA[PA];
    size_t srcA0[PA], srcA1[PA];
#pragma unroll
    for (int p = 0; p < PA; ++p) {
        rA[p] = p * 64 + (tid >> 2);
        swA[p] = rA[p] & 7;
        srcA0[p] = (size_t)(bm + rA[p]) * lda + ((c0 ^ swA[p]) << 3);
        srcA1[p] = (size_t)(bm + rA[p]) * lda + ((c1 ^ swA[p]) << 3);
    }
    int rB = tid >> 2, swB = rB & 7;
    size_t srcB0 = (size_t)(bn + rB) * ldb + ((c0 ^ swB) << 3);
    size_t srcB1 = (size_t)(bn + rB) * ldb + ((c1 ^ swB) << 3);

    floatx4 acc[MI][2];
#pragma unroll
    for (int i = 0; i < MI; ++i)
#pragma unroll
        for (int j = 0; j < 2; ++j) acc[i][j] = (floatx4){0.f, 0.f, 0.f, 0.f};

    bf16x8 pa0[PA], pa1[PA], pb0, pb1;
#pragma unroll
    for (int p = 0; p < PA; ++p) {
        pa0[p] = *(const bf16x8*)(A + srcA0[p]);
        pa1[p] = *(const bf16x8*)(A + srcA1[p]);
    }
    pb0 = *(const bf16x8*)(Bt + srcB0);
    pb1 = *(const bf16x8*)(Bt + srcB1);
#pragma unroll
    for (int p = 0; p < PA; ++p) {
        *(bf16x8*)&sA[p * 4096 + tid * 16] = pa0[p];
        *(bf16x8*)&sA[p * 4096 + tid * 16 + 8] = pa1[p];
    }
    *(bf16x8*)&sB[tid * 16] = pb0;
    *(bf16x8*)&sB[tid * 16 + 8] = pb1;
    __syncthreads();

    for (int k0 = 0; k0 < K; k0 += 64) {
        int kn = (k0 + 64 < K) ? k0 + 64 : 0;
#pragma unroll
        for (int p = 0; p < PA; ++p) {
            pa0[p] = *(const bf16x8*)(A + srcA0[p] + kn);
            pa1[p] = *(const bf16x8*)(A + srcA1[p] + kn);
        }
        pb0 = *(const bf16x8*)(Bt + srcB0 + kn);
        pb1 = *(const bf16x8*)(Bt + srcB1 + kn);

#pragma unroll
        for (int s = 0; s < 2; ++s) {
            int cs = s * 4 + q;
            bf16x8 af[MI], bfr[2];
#pragma unroll
            for (int i = 0; i < MI; ++i) {
                int row = wm + i * 16 + lm;
                af[i] = *(bf16x8*)&sA[row * 64 + ((cs ^ (lm & 7)) << 3)];
            }
#pragma unroll
            for (int j = 0; j < 2; ++j) {
                int row = wn + j * 16 + lm;
                bfr[j] = *(bf16x8*)&sB[row * 64 + ((cs ^ (lm & 7)) << 3)];
            }
#pragma unroll
            for (int i = 0; i < MI; ++i)
#pragma unroll
                for (int j = 0; j < 2; ++j)
                    acc[i][j] = mfma16(af[i], bfr[j], acc[i][j]);
        }

        __syncthreads();
#pragma unroll
        for (int p = 0; p < PA; ++p) {
            *(bf16x8*)&sA[p * 4096 + tid * 16] = pa0[p];
            *(bf16x8*)&sA[p * 4096 + tid * 16 + 8] = pa1[p];
        }
        *(bf16x8*)&sB[tid * 16] = pb0;
        *(bf16x8*)&sB[tid * 16 + 8] = pb1;
        __syncthreads();
    }

    // C/D layout: col = lane&15, row = (lane>>4)*4 + reg  [m89/m91 verified]
#pragma unroll
    for (int i = 0; i < MI; ++i)
#pragma unroll
        for (int j = 0; j < 2; ++j)
#pragma unroll
            for (int r = 0; r < 4; ++r) {
                int row = bm + wm + i * 16 + q * 4 + r;
                int col = bn + wn + j * 16 + lm;
                float v = acc[i][j][r];
                if (col < qcols) v *= qscale;
                if (bias) v += bias[col];
                if (col >= vt_col0) {
                    int cc = col - vt_col0;
                    VtOut[(size_t)(cc & 63) * 16384 + row * 8 + (cc >> 6)] = (bf16_t)v;
                } else {
                    size_t off = (size_t)row * ldc + col;
                    if (OF32) ((float*)Cout)[off] = v;
                    else      ((bf16_t*)Cout)[off] = (bf16_t)v;
                }
            }
}

// ---------------- flash attention r24: 32x32x16 MFMA, S^T formulation ----------------
// Per 64-key tile: 2 key sub-tiles ts (32 keys) x 2 qrow blocks sq (32 rows).
// sK staged sigma-permuted: LDS row 32ts+p holds logical key 32ts+sig(p),
// sig(p) = p^12 iff ((p>>2)&3) in {1,2}. Then lane (h=lane>>5) S regs [8t..8t+7]
// hold logical keys 16t+8h+{0..7} == PV B-operand slots k=(lane>>5)*8+j.
// QK unit: S = sum_c mfma32(kf[ts][c], qf[sq][c]) (A row=key=lane&31, k-half by h).
// PV: A = V^T frag (row dh=32nd2+lane&31, 8 keys, chunk-swizzled), B = bf16(S regs).
// O^T acc[sq][nd2] floatx16: qrow=lane&31, dh=(reg&3)+8*(reg>>2)+4h+32nd2.
__global__ __launch_bounds__(256, 2) void flash_attn(const bf16_t* __restrict__ QK,
                                                     const bf16_t* __restrict__ Vt,
                                                     bf16_t* __restrict__ O,
                                                     float* __restrict__ accP,
                                                     float* __restrict__ lP,
                                                     int kps, int nsplit) {
    __shared__ bf16_t sK[2][64 * 64];   // (sigma-permuted key, dh-chunk')
    __shared__ bf16_t sVt[2][64 * 64];  // (dh, natural key-chunk')
    int tid = threadIdx.x;
    int wave = tid >> 6, lane = tid & 63;
    int lr = lane & 31, l5 = lane >> 5;
    int sp = blockIdx.y;
    int qrow0 = blockIdx.x * 256 + wave * 64;

    // Q frags: qf[sq][c] = Q[qrow0+32sq+lr][16c + 8*l5 .. +7]
    bf16x8 qf[2][4];
#pragma unroll
    for (int sq = 0; sq < 2; ++sq) {
        int qr = qrow0 + sq * 32 + lr;
        const bf16_t* qp = QK + (size_t)(qr >> 3) * 1024 + (qr & 7) * 64 + l5 * 8;
#pragma unroll
        for (int c = 0; c < 4; ++c)
            qf[sq][c] = *(const bf16x8*)(qp + c * 16);
    }

    // staging: thread covers LDS [tid*16,+16); chunk swizzle ^(row&7) folded into source.
    int sr = tid >> 2;
    int ch0 = (tid & 3) * 2, ch1 = ch0 + 1;
    int swz = sr & 7;
    int p_ = sr & 31;
    int b4 = (p_ >> 2) & 3;
    int sig = (b4 == 1 || b4 == 2) ? (p_ ^ 12) : p_;
    int lsr = (sr & 32) + sig;  // logical key within 64-key tile
    int ksrcA = (lsr >> 3) * 1024 + (lsr & 7) * 64 + 512 + ((ch0 ^ swz) << 3);
    int ksrcB = (lsr >> 3) * 1024 + (lsr & 7) * 64 + 512 + ((ch1 ^ swz) << 3);
    size_t vsrcA = (size_t)sr * 16384 + ((ch0 ^ swz) << 3);
    size_t vsrcB = (size_t)sr * 16384 + ((ch1 ^ swz) << 3);

    floatx16 acc[2][2];  // [sq][nd2]
#pragma unroll
    for (int sq = 0; sq < 2; ++sq)
#pragma unroll
        for (int i = 0; i < 2; ++i) acc[sq][i] = F16_ZERO;
    float lacc[2] = {0.f, 0.f};

    int kt0 = sp * kps, kend = kt0 + kps;

    bf16x8 krA, krB, vrA, vrB;
    {
        const bf16_t* kb = QK + (size_t)kt0 * 128;
        krA = *(const bf16x8*)(kb + ksrcA);
        krB = *(const bf16x8*)(kb + ksrcB);
        vrA = *(const bf16x8*)(Vt + vsrcA + kt0);
        vrB = *(const bf16x8*)(Vt + vsrcB + kt0);
    }
    *(bf16x8*)&sK[0][tid * 16] = krA; *(bf16x8*)&sK[0][tid * 16 + 8] = krB;
    *(bf16x8*)&sVt[0][tid * 16] = vrA; *(bf16x8*)&sVt[0][tid * 16 + 8] = vrB;
    __syncthreads();

// QK unit: S = sum over dh-chunks c of K-frag(ts,c) x Q-frag(sq,c)
#define QK_U(S, ts, sq)                                        \
    {                                                          \
        floatx16 a_ = F16_ZERO;                                \
        _Pragma("unroll")                                      \
        for (int c = 0; c < 4; ++c)                            \
            a_ = mfma32(kf[ts][c], qf[sq][c], a_);             \
        S = a_;                                                \
    }

// softmax + PV unit: exp2 16 regs, pack regs [0..7]/[8..15] -> PV B-operands,
// 4 mfma32 into acc[sq][*]
#define SMPV_U(S, ts, sq)                                                            \
    {                                                                                \
        _Pragma("unroll")                                                            \
        for (int r = 0; r < 16; ++r) {                                               \
            float pv_ = __builtin_amdgcn_exp2f(S[r]);                                \
            S[r] = pv_;                                                              \
            lacc[sq] += pv_;                                                         \
        }                                                                            \
        bf16x8 pf0_, pf1_;                                                           \
        _Pragma("unroll")                                                            \
        for (int r = 0; r < 8; ++r) {                                                \
            pf0_[r] = (bf16_t)S[r];                                                  \
            pf1_[r] = (bf16_t)S[r + 8];                                              \
        }                                                                            \
        _Pragma("unroll")                                                            \
        for (int nd2 = 0; nd2 < 2; ++nd2) {                                          \
            int row_ = (nd2 * 32 + lr) * 64;                                         \
            bf16x8 v0_ = *(const bf16x8*)&cV[row_ + ((((ts)*4 + l5) ^ (lr & 7)) << 3)];     \
            bf16x8 v1_ = *(const bf16x8*)&cV[row_ + ((((ts)*4 + 2 + l5) ^ (lr & 7)) << 3)]; \
            acc[sq][nd2] = mfma32(v0_, pf0_, acc[sq][nd2]);                          \
            acc[sq][nd2] = mfma32(v1_, pf1_, acc[sq][nd2]);                          \
        }                                                                            \
    }

    int cur = 0;
    for (int kt = kt0; kt < kend; kt += 64) {
        int ktn = (kt + 64 < kend) ? kt + 64 : kt0;
        const bf16_t* kbn = QK + (size_t)ktn * 128;
        krA = *(const bf16x8*)(kbn + ksrcA);
        krB = *(const bf16x8*)(kbn + ksrcB);
        vrA = *(const bf16x8*)(Vt + vsrcA + ktn);
        vrB = *(const bf16x8*)(Vt + vsrcB + ktn);

        const bf16_t* cK = sK[cur];
        const bf16_t* cV = sVt[cur];

        // hoist K fragments once per tile (8 ds_read_b128)
        bf16x8 kf[2][4];
#pragma unroll
        for (int ts = 0; ts < 2; ++ts)
#pragma unroll
            for (int c = 0; c < 4; ++c)
                kf[ts][c] = *(const bf16x8*)
                    &cK[(ts * 32 + lr) * 64 + (((2 * c + l5) ^ (lr & 7)) << 3)];

        // 4 units (ts,sq), QK(i+1) ahead of SM+PV(i)
        floatx16 sA_, sB_;
        QK_U(sA_, 0, 0);
        QK_U(sB_, 0, 1);
        SMPV_U(sA_, 0, 0);
        QK_U(sA_, 1, 0);
        SMPV_U(sB_, 0, 1);
        QK_U(sB_, 1, 1);
        SMPV_U(sA_, 1, 0);
        SMPV_U(sB_, 1, 1);

        // write next tile into the idle buffer; ONE barrier publishes it and
        // retires buf[cur].
        bf16_t* nK = &sK[cur ^ 1][tid * 16];
        bf16_t* nV = &sVt[cur ^ 1][tid * 16];
        *(bf16x8*)nK = krA; *(bf16x8*)(nK + 8) = krB;
        *(bf16x8*)nV = vrA; *(bf16x8*)(nV + 8) = vrB;
        __syncthreads();
        cur ^= 1;
    }
#undef QK_U
#undef SMPV_U

    // l reduction: lanes l and l+32 hold disjoint key halves of the same qrow
    lacc[0] += __shfl_xor(lacc[0], 32);
    lacc[1] += __shfl_xor(lacc[1], 32);

    if (nsplit == 1) {
#pragma unroll
        for (int sq = 0; sq < 2; ++sq) {
            float inv = 1.f / lacc[sq];
            int row = qrow0 + sq * 32 + lr;
#pragma unroll
            for (int nd2 = 0; nd2 < 2; ++nd2)
#pragma unroll
                for (int g = 0; g < 4; ++g) {
                    bf16x4 o;
#pragma unroll
                    for (int r = 0; r < 4; ++r)
                        o[r] = (bf16_t)(acc[sq][nd2][4 * g + r] * inv);
                    int dh = nd2 * 32 + 8 * g + 4 * l5;
                    *(bf16x4*)&O[(size_t)row * 64 + dh] = o;
                }
        }
    } else {
#pragma unroll
        for (int sq = 0; sq < 2; ++sq) {
            int row = qrow0 + sq * 32 + lr;
            size_t base = ((size_t)sp * 16384 + row) * 64;
#pragma unroll
            for (int nd2 = 0; nd2 < 2; ++nd2)
#pragma unroll
                for (int g = 0; g < 4; ++g) {
                    float4 v = {acc[sq][nd2][4 * g], acc[sq][nd2][4 * g + 1],
                                acc[sq][nd2][4 * g + 2], acc[sq][nd2][4 * g + 3]};
                    int dh = nd2 * 32 + 8 * g + 4 * l5;
                    *(float4*)&accP[base + dh] = v;
                }
            if (lane < 32) lP[sp * 16384 + row] = lacc[sq];
        }
    }
}

// ---------------- merge key-split partials (plain sums) ----------------
__global__ __launch_bounds__(256) void merge_attn(const float* __restrict__ accP,
                                                  const float* __restrict__ lP,
                                                  bf16_t* __restrict__ O, int nsplit) {
    int idx = blockIdx.x * 256 + threadIdx.x;
    int row = idx >> 4, dh4 = (idx & 15) * 4;
    float4 num = {0.f, 0.f, 0.f, 0.f};
    float den = 0.f;
    for (int s = 0; s < nsplit; ++s) {
        float4 a = *(const float4*)&accP[((size_t)s * 16384 + row) * 64 + dh4];
        num.x += a.x; num.y += a.y; num.z += a.z; num.w += a.w;
        den += lP[s * 16384 + row];
    }
    float inv = 1.f / den;
    bf16x4 o;
    o[0] = (bf16_t)(num.x * inv); o[1] = (bf16_t)(num.y * inv);
    o[2] = (bf16_t)(num.z * inv); o[3] = (bf16_t)(num.w * inv);
    *(bf16x4*)&O[(size_t)row * 64 + dh4] = o;
}

// ---------------- launch ----------------
extern "C" void kernel_launch(void* const* d_in, const int* in_sizes, int n_in,
                              void* d_out, int out_size, void* d_ws, size_t ws_size,
                              hipStream_t stream) {
    const float* x    = (const float*)d_in[0];  // 2048 x 1024
    const float* Wq   = (const float*)d_in[1];  // 1024 x 512
    const float* Wkv  = (const float*)d_in[2];  // 1024 x 1024
    const float* Wout = (const float*)d_in[3];  // 512 x 1024
    const float* bout = (const float*)d_in[4];  // 1024

    char* ws = (char*)d_ws;
    bf16_t* QK    = (bf16_t*)ws;
    bf16_t* Vt    = (bf16_t*)(ws + 4194304);
    bf16_t* Ob    = (bf16_t*)(ws + 6291456);
    bf16_t* xb    = (bf16_t*)(ws + 8388608);
    bf16_t* WtQKV = (bf16_t*)(ws + 12582912);
    bf16_t* WtOut = (bf16_t*)(ws + 15728640);
    float*  accP  = (float*)(ws + 16777216);

    int nsplit = (ws_size >= (size_t)16777216 + 8 * 4259840) ? 8
               : (ws_size >= (size_t)16777216 + 4 * 4259840) ? 4
               : (ws_size >= (size_t)16777216 + 2 * 4259840) ? 2 : 1;
    float* lP = (float*)(ws + 16777216 + (size_t)nsplit * 4194304);

    prep_all<<<3072, 256, 0, stream>>>(x, xb, Wq, Wkv, Wout, WtQKV, WtOut);

    // [QK | Vt] = xb @ WtQKV^T; Q cols scaled by DH^-0.5*log2(e); V cols transposed
    gemm_bt<0, 2><<<dim3(32, 24), 256, 0, stream>>>(
        xb, WtQKV, nullptr, QK, Vt, 1024, 1024, 1024, 1024, 1024,
        0.18033688011112042f, 512);

    flash_attn<<<dim3(64, nsplit), 256, 0, stream>>>(QK, Vt, Ob, accP, lP,
                                                     16384 / nsplit, nsplit);
    if (nsplit > 1)
        merge_attn<<<1024, 256, 0, stream>>>(accP, lP, Ob, nsplit);

    // out = Ob @ WtOut^T + bout (fp32 out)
    gemm_bt<1, 2><<<dim3(32, 16), 256, 0, stream>>>(
        Ob, WtOut, bout, d_out, nullptr, 1 << 30, 512, 512, 512, 1024,
        1.0f, 0);
}

// Round 11
// 169.715 us; speedup vs baseline: 1.0425x; 1.0425x over previous
//
#include <hip/hip_runtime.h>
#include <hip/hip_bf16.h>
#include <stdint.h>

// B=2048, D=1024, H=8, DH=64, INNER=512; attention over flattened (B*H)=16384 axis.
// fp32 in/out. Pipeline:
//   prep_all: x->xb bf16; weights -> transposed bf16
//   GEMM-1: xb @ WtQKV^T -> QK (Q pre-scaled) + Vt (V transposed)
//   flash attention r19 (BEST MEASURED, 170.1us total): LDS double-buffer,
//     ONE barrier/tile, sub-granular QK(i+1) || SM+PV(i) software pipeline,
//     16x16x32 MFMA (16-row frags -> 2-way LDS conflicts = free; r24's 32x32
//     frags were structurally 4-way on 128B rows -> neutral, reverted).
//   merge -> GEMM-2: Ob @ WtOut^T + bias -> fp32 out.
// Session evidence: 9 structural variants (occupancy, barriers, no-LDS, layouts,
// GEMM tiles, fused merge, stagger, 32x32) all <= this config; flash is at the
// plain-HIP attention plateau (~930 TF), non-flash at small-GEMM + dispatch
// overhead floor. This is the converged configuration.
// ws: QK 4M | Vt 2M | Ob 2M | xb 4M | WtQKV 3M | WtOut 1M | accP ns*4M | lP ns*64K.

typedef __bf16 bf16_t;
typedef __bf16 bf16x4 __attribute__((ext_vector_type(4)));
typedef __bf16 bf16x8 __attribute__((ext_vector_type(8)));
typedef float floatx4 __attribute__((ext_vector_type(4)));

__device__ __forceinline__ floatx4 mfma16(bf16x8 a, bf16x8 b, floatx4 c) {
    return __builtin_amdgcn_mfma_f32_16x16x32_bf16(a, b, c, 0, 0, 0);
}

__device__ __forceinline__ bf16x8 cvt8(float4 a, float4 b) {
    bf16x8 o;
    o[0] = (bf16_t)a.x; o[1] = (bf16_t)a.y; o[2] = (bf16_t)a.z; o[3] = (bf16_t)a.w;
    o[4] = (bf16_t)b.x; o[5] = (bf16_t)b.y; o[6] = (bf16_t)b.z; o[7] = (bf16_t)b.w;
    return o;
}

// ---------------- fused prep (r14, unchanged) ----------------
__device__ __forceinline__ void transpose_body(const float* __restrict__ in, int N,
                                               bf16_t* __restrict__ out, int ldo,
                                               int bx, int by, int tid, float (*tile)[33]) {
    int n0 = bx * 32, k0 = by * 32;
    int tx = tid & 31, ty = tid >> 5;
#pragma unroll
    for (int i = 0; i < 32; i += 8)
        tile[ty + i][tx] = in[(size_t)(k0 + ty + i) * N + (n0 + tx)];
    __syncthreads();
#pragma unroll
    for (int i = 0; i < 32; i += 8)
        out[(size_t)(n0 + ty + i) * ldo + (k0 + tx)] = (bf16_t)tile[tx][ty + i];
}

__global__ __launch_bounds__(256) void prep_all(const float* __restrict__ x,
                                                bf16_t* __restrict__ xb,
                                                const float* __restrict__ Wq,
                                                const float* __restrict__ Wkv,
                                                const float* __restrict__ Wout,
                                                bf16_t* __restrict__ WtQKV,
                                                bf16_t* __restrict__ WtOut) {
    __shared__ float tile[32][33];
    int b = blockIdx.x, tid = threadIdx.x;
    if (b < 1024) {
        int i = (b * 256 + tid) * 8;
        *(bf16x8*)(xb + i) = cvt8(*(const float4*)(x + i), *(const float4*)(x + i + 4));
    } else if (b < 1536) {
        b -= 1024;
        transpose_body(Wq, 512, WtQKV, 1024, b & 15, b >> 4, tid, tile);
    } else if (b < 2560) {
        b -= 1536;
        transpose_body(Wkv, 1024, WtQKV + 512 * 1024, 1024, b & 31, b >> 5, tid, tile);
    } else {
        b -= 2560;
        transpose_body(Wout, 1024, WtOut, 512, b & 31, b >> 5, tid, tile);
    }
}

// ---------------- GEMM (r13/r14-proven, unchanged) ----------------
template <int OF32, int MI>
__global__ __launch_bounds__(256) void gemm_bt(const bf16_t* __restrict__ A,
                                               const bf16_t* __restrict__ Bt,
                                               const float* __restrict__ bias,
                                               void* __restrict__ Cout,
                                               bf16_t* __restrict__ VtOut, int vt_col0,
                                               int K, int lda, int ldb, int ldc,
                                               float qscale, int qcols) {
    constexpr int MT = MI * 32;
    constexpr int PA = MT / 64;
    __shared__ bf16_t sA[MT * 64];
    __shared__ bf16_t sB[64 * 64];
    int tid = threadIdx.x;
    int wave = tid >> 6, lane = tid & 63;
    int lm = lane & 15, q = lane >> 4;
    int bm = blockIdx.x * MT, bn = blockIdx.y * 64;
    int wm = (wave >> 1) * (MT / 2), wn = (wave & 1) * 32;

    int c0 = (tid & 3) * 2, c1 = c0 + 1;
    int rA[PA], swA[PA];
    size_t srcA0[PA], srcA1[PA];
#pragma unroll
    for (int p = 0; p < PA; ++p) {
        rA[p] = p * 64 + (tid >> 2);
        swA[p] = rA[p] & 7;
        srcA0[p] = (size_t)(bm + rA[p]) * lda + ((c0 ^ swA[p]) << 3);
        srcA1[p] = (size_t)(bm + rA[p]) * lda + ((c1 ^ swA[p]) << 3);
    }
    int rB = tid >> 2, swB = rB & 7;
    size_t srcB0 = (size_t)(bn + rB) * ldb + ((c0 ^ swB) << 3);
    size_t srcB1 = (size_t)(bn + rB) * ldb + ((c1 ^ swB) << 3);

    floatx4 acc[MI][2];
#pragma unroll
    for (int i = 0; i < MI; ++i)
#pragma unroll
        for (int j = 0; j < 2; ++j) acc[i][j] = (floatx4){0.f, 0.f, 0.f, 0.f};

    bf16x8 pa0[PA], pa1[PA], pb0, pb1;
#pragma unroll
    for (int p = 0; p < PA; ++p) {
        pa0[p] = *(const bf16x8*)(A + srcA0[p]);
        pa1[p] = *(const bf16x8*)(A + srcA1[p]);
    }
    pb0 = *(const bf16x8*)(Bt + srcB0);
    pb1 = *(const bf16x8*)(Bt + srcB1);
#pragma unroll
    for (int p = 0; p < PA; ++p) {
        *(bf16x8*)&sA[p * 4096 + tid * 16] = pa0[p];
        *(bf16x8*)&sA[p * 4096 + tid * 16 + 8] = pa1[p];
    }
    *(bf16x8*)&sB[tid * 16] = pb0;
    *(bf16x8*)&sB[tid * 16 + 8] = pb1;
    __syncthreads();

    for (int k0 = 0; k0 < K; k0 += 64) {
        int kn = (k0 + 64 < K) ? k0 + 64 : 0;
#pragma unroll
        for (int p = 0; p < PA; ++p) {
            pa0[p] = *(const bf16x8*)(A + srcA0[p] + kn);
            pa1[p] = *(const bf16x8*)(A + srcA1[p] + kn);
        }
        pb0 = *(const bf16x8*)(Bt + srcB0 + kn);
        pb1 = *(const bf16x8*)(Bt + srcB1 + kn);

#pragma unroll
        for (int s = 0; s < 2; ++s) {
            int cs = s * 4 + q;
            bf16x8 af[MI], bfr[2];
#pragma unroll
            for (int i = 0; i < MI; ++i) {
                int row = wm + i * 16 + lm;
                af[i] = *(bf16x8*)&sA[row * 64 + ((cs ^ (lm & 7)) << 3)];
            }
#pragma unroll
            for (int j = 0; j < 2; ++j) {
                int row = wn + j * 16 + lm;
                bfr[j] = *(bf16x8*)&sB[row * 64 + ((cs ^ (lm & 7)) << 3)];
            }
#pragma unroll
            for (int i = 0; i < MI; ++i)
#pragma unroll
                for (int j = 0; j < 2; ++j)
                    acc[i][j] = mfma16(af[i], bfr[j], acc[i][j]);
        }

        __syncthreads();
#pragma unroll
        for (int p = 0; p < PA; ++p) {
            *(bf16x8*)&sA[p * 4096 + tid * 16] = pa0[p];
            *(bf16x8*)&sA[p * 4096 + tid * 16 + 8] = pa1[p];
        }
        *(bf16x8*)&sB[tid * 16] = pb0;
        *(bf16x8*)&sB[tid * 16 + 8] = pb1;
        __syncthreads();
    }

    // C/D layout: col = lane&15, row = (lane>>4)*4 + reg  [m89/m91 verified]
#pragma unroll
    for (int i = 0; i < MI; ++i)
#pragma unroll
        for (int j = 0; j < 2; ++j)
#pragma unroll
            for (int r = 0; r < 4; ++r) {
                int row = bm + wm + i * 16 + q * 4 + r;
                int col = bn + wn + j * 16 + lm;
                float v = acc[i][j][r];
                if (col < qcols) v *= qscale;
                if (bias) v += bias[col];
                if (col >= vt_col0) {
                    int cc = col - vt_col0;
                    VtOut[(size_t)(cc & 63) * 16384 + row * 8 + (cc >> 6)] = (bf16_t)v;
                } else {
                    size_t off = (size_t)row * ldc + col;
                    if (OF32) ((float*)Cout)[off] = v;
                    else      ((bf16_t*)Cout)[off] = (bf16_t)v;
                }
            }
}

// ---------------- flash attention r19: intra-wave sub-pipelined, LDS dbuf ----------------
// S^T = K·Q^T (A=K-frag, B=Q-frag) -> C[key=4q+r][qrow=lm]. sK staged with key
// permutation sigma: LDS row 16nb+m holds logical key 32(nb>>1)+8(m>>2)+4(nb&1)+(m&3),
// so S regs nb-pairs (2jb,2jb+1) give keys 32jb+8q+{0..3,4..7} == PV B-operand layout.
// O^T = V^T·P^T: A=V-frag from sVt (natural key order), B=packed exp2 regs.
// Per-tile schedule (sub = 16 q-rows): QK(i+1) issued BEFORE softmax(i) so its
// MFMAs occupy the matrix pipe while exp2(i) runs on the trans pipe; PV(i) follows.
__global__ __launch_bounds__(256, 2) void flash_attn(const bf16_t* __restrict__ QK,
                                                     const bf16_t* __restrict__ Vt,
                                                     bf16_t* __restrict__ O,
                                                     float* __restrict__ accP,
                                                     float* __restrict__ lP,
                                                     int kps, int nsplit) {
    __shared__ bf16_t sK[2][64 * 64];   // (sigma-permuted key, dh-chunk')
    __shared__ bf16_t sVt[2][64 * 64];  // (dh, natural key-chunk')
    int tid = threadIdx.x;
    int wave = tid >> 6, lane = tid & 63;
    int lm = lane & 15, q = lane >> 4;
    int sp = blockIdx.y;
    int qrow0 = blockIdx.x * 256 + wave * 64;

    bf16x8 qf[4][2];
#pragma unroll
    for (int sub = 0; sub < 4; ++sub) {
        int qr = qrow0 + sub * 16 + lm;
        const bf16_t* qp = QK + (size_t)(qr >> 3) * 1024 + (qr & 7) * 64;
        qf[sub][0] = *(const bf16x8*)(qp + q * 8);
        qf[sub][1] = *(const bf16x8*)(qp + 32 + q * 8);
    }

    // staging: thread covers LDS [tid*16,+16); chunk swizzle ^(row&7) folded into source.
    int sr = tid >> 2;
    int ch0 = (tid & 3) * 2, ch1 = ch0 + 1;
    int swz = sr & 7;
    int lsr = 32 * (sr >> 5) + 8 * ((sr >> 2) & 3) + 4 * ((sr >> 4) & 1) + (sr & 3);
    int ksrcA = (lsr >> 3) * 1024 + (lsr & 7) * 64 + 512 + ((ch0 ^ swz) << 3);
    int ksrcB = (lsr >> 3) * 1024 + (lsr & 7) * 64 + 512 + ((ch1 ^ swz) << 3);
    size_t vsrcA = (size_t)sr * 16384 + ((ch0 ^ swz) << 3);
    size_t vsrcB = (size_t)sr * 16384 + ((ch1 ^ swz) << 3);

    int c0 = q ^ (lm & 7);  // chunk-swizzled read column

    floatx4 acc[4][4];  // [sub][nd]: O^T, dh = 16nd+4q+r, qrow = 16sub+lm
#pragma unroll
    for (int sub = 0; sub < 4; ++sub)
#pragma unroll
        for (int i = 0; i < 4; ++i) acc[sub][i] = (floatx4){0.f, 0.f, 0.f, 0.f};
    float lacc[4] = {0.f, 0.f, 0.f, 0.f};  // per-lane partial row sums (qrow=lm)

    int kt0 = sp * kps, kend = kt0 + kps;

    bf16x8 krA, krB, vrA, vrB;
    {
        const bf16_t* kb = QK + (size_t)kt0 * 128;
        krA = *(const bf16x8*)(kb + ksrcA);
        krB = *(const bf16x8*)(kb + ksrcB);
        vrA = *(const bf16x8*)(Vt + vsrcA + kt0);
        vrB = *(const bf16x8*)(Vt + vsrcB + kt0);
    }
    *(bf16x8*)&sK[0][tid * 16] = krA; *(bf16x8*)&sK[0][tid * 16 + 8] = krB;
    *(bf16x8*)&sVt[0][tid * 16] = vrA; *(bf16x8*)&sVt[0][tid * 16 + 8] = vrB;
    __syncthreads();

// QK for one sub (pure-reg: uses hoisted kf0/kf1): S[nb] = K-frag(nb) x Q(sub)
#define QK_SUB(S, sub)                                          \
    _Pragma("unroll")                                           \
    for (int nb = 0; nb < 4; ++nb) {                            \
        floatx4 a_ = (floatx4){0.f, 0.f, 0.f, 0.f};             \
        a_ = mfma16(kf0[nb], qf[sub][0], a_);                   \
        a_ = mfma16(kf1[nb], qf[sub][1], a_);                   \
        S[nb] = a_;                                             \
    }

// softmax + PV for one sub: exp2/row-sum, pack to PV B-operands, 8 MFMA into acc
#define SMPV_SUB(S, sub)                                                  \
    {                                                                     \
        _Pragma("unroll")                                                 \
        for (int nb = 0; nb < 4; ++nb)                                    \
            _Pragma("unroll")                                             \
            for (int r = 0; r < 4; ++r) {                                 \
                float pv_ = __builtin_amdgcn_exp2f(S[nb][r]);             \
                S[nb][r] = pv_;                                           \
                lacc[sub] += pv_;                                         \
            }                                                             \
        bf16x8 p0_, p1_;                                                  \
        _Pragma("unroll")                                                 \
        for (int r = 0; r < 4; ++r) {                                     \
            p0_[r] = (bf16_t)S[0][r]; p0_[r + 4] = (bf16_t)S[1][r];       \
            p1_[r] = (bf16_t)S[2][r]; p1_[r + 4] = (bf16_t)S[3][r];       \
        }                                                                 \
        _Pragma("unroll")                                                 \
        for (int nd = 0; nd < 4; ++nd) {                                  \
            int row_ = (nd * 16 + lm) * 64;                               \
            bf16x8 v0_ = *(const bf16x8*)&cV[row_ + (c0 << 3)];           \
            bf16x8 v1_ = *(const bf16x8*)&cV[row_ + ((c0 ^ 4) << 3)];     \
            acc[sub][nd] = mfma16(v0_, p0_, acc[sub][nd]);                \
            acc[sub][nd] = mfma16(v1_, p1_, acc[sub][nd]);                \
        }                                                                 \
    }

    int cur = 0;
    for (int kt = kt0; kt < kend; kt += 64) {
        int ktn = (kt + 64 < kend) ? kt + 64 : kt0;
        const bf16_t* kbn = QK + (size_t)ktn * 128;
        krA = *(const bf16x8*)(kbn + ksrcA);
        krB = *(const bf16x8*)(kbn + ksrcB);
        vrA = *(const bf16x8*)(Vt + vsrcA + ktn);
        vrB = *(const bf16x8*)(Vt + vsrcB + ktn);

        const bf16_t* cK = sK[cur];
        const bf16_t* cV = sVt[cur];

        // hoist K fragments once per tile (8 ds_read_b128); QK_SUB is then pure-reg
        bf16x8 kf0[4], kf1[4];
#pragma unroll
        for (int nb = 0; nb < 4; ++nb) {
            int row = (nb * 16 + lm) * 64;
            kf0[nb] = *(const bf16x8*)&cK[row + (c0 << 3)];
            kf1[nb] = *(const bf16x8*)&cK[row + ((c0 ^ 4) << 3)];
        }

        // sub-granular software pipeline: QK(i+1) ahead of SM+PV(i)
        floatx4 sEv[4], sOd[4];
        QK_SUB(sEv, 0);
        QK_SUB(sOd, 1);
        SMPV_SUB(sEv, 0);
        QK_SUB(sEv, 2);
        SMPV_SUB(sOd, 1);
        QK_SUB(sOd, 3);
        SMPV_SUB(sEv, 2);
        SMPV_SUB(sOd, 3);

        // write next tile into the idle buffer; ONE barrier publishes it and
        // retires buf[cur] (all reads of buf[cur] are program-order before it).
        bf16_t* nK = &sK[cur ^ 1][tid * 16];
        bf16_t* nV = &sVt[cur ^ 1][tid * 16];
        *(bf16x8*)nK = krA; *(bf16x8*)(nK + 8) = krB;
        *(bf16x8*)nV = vrA; *(bf16x8*)(nV + 8) = vrB;
        __syncthreads();
        cur ^= 1;
    }
#undef QK_SUB
#undef SMPV_SUB

    // l reduction: lanes sharing lm across the 4 quads hold disjoint key subsets
#pragma unroll
    for (int sub = 0; sub < 4; ++sub) {
        lacc[sub] += __shfl_xor(lacc[sub], 16);
        lacc[sub] += __shfl_xor(lacc[sub], 32);
    }

    if (nsplit == 1) {
#pragma unroll
        for (int sub = 0; sub < 4; ++sub) {
            float inv = 1.f / lacc[sub];
            int row = qrow0 + sub * 16 + lm;
#pragma unroll
            for (int nd = 0; nd < 4; ++nd) {
                bf16x4 o;
#pragma unroll
                for (int r = 0; r < 4; ++r) o[r] = (bf16_t)(acc[sub][nd][r] * inv);
                *(bf16x4*)&O[(size_t)row * 64 + nd * 16 + q * 4] = o;
            }
        }
    } else {
#pragma unroll
        for (int sub = 0; sub < 4; ++sub) {
            int row = qrow0 + sub * 16 + lm;
            size_t base = ((size_t)sp * 16384 + row) * 64;
#pragma unroll
            for (int nd = 0; nd < 4; ++nd) {
                float4 v = {acc[sub][nd][0], acc[sub][nd][1],
                            acc[sub][nd][2], acc[sub][nd][3]};
                *(float4*)&accP[base + nd * 16 + q * 4] = v;
            }
            if (lane < 16) lP[sp * 16384 + row] = lacc[sub];
        }
    }
}

// ---------------- merge key-split partials (plain sums) ----------------
__global__ __launch_bounds__(256) void merge_attn(const float* __restrict__ accP,
                                                  const float* __restrict__ lP,
                                                  bf16_t* __restrict__ O, int nsplit) {
    int idx = blockIdx.x * 256 + threadIdx.x;
    int row = idx >> 4, dh4 = (idx & 15) * 4;
    float4 num = {0.f, 0.f, 0.f, 0.f};
    float den = 0.f;
    for (int s = 0; s < nsplit; ++s) {
        float4 a = *(const float4*)&accP[((size_t)s * 16384 + row) * 64 + dh4];
        num.x += a.x; num.y += a.y; num.z += a.z; num.w += a.w;
        den += lP[s * 16384 + row];
    }
    float inv = 1.f / den;
    bf16x4 o;
    o[0] = (bf16_t)(num.x * inv); o[1] = (bf16_t)(num.y * inv);
    o[2] = (bf16_t)(num.z * inv); o[3] = (bf16_t)(num.w * inv);
    *(bf16x4*)&O[(size_t)row * 64 + dh4] = o;
}

// ---------------- launch ----------------
extern "C" void kernel_launch(void* const* d_in, const int* in_sizes, int n_in,
                              void* d_out, int out_size, void* d_ws, size_t ws_size,
                              hipStream_t stream) {
    const float* x    = (const float*)d_in[0];  // 2048 x 1024
    const float* Wq   = (const float*)d_in[1];  // 1024 x 512
    const float* Wkv  = (const float*)d_in[2];  // 1024 x 1024
    const float* Wout = (const float*)d_in[3];  // 512 x 1024
    const float* bout = (const float*)d_in[4];  // 1024

    char* ws = (char*)d_ws;
    bf16_t* QK    = (bf16_t*)ws;
    bf16_t* Vt    = (bf16_t*)(ws + 4194304);
    bf16_t* Ob    = (bf16_t*)(ws + 6291456);
    bf16_t* xb    = (bf16_t*)(ws + 8388608);
    bf16_t* WtQKV = (bf16_t*)(ws + 12582912);
    bf16_t* WtOut = (bf16_t*)(ws + 15728640);
    float*  accP  = (float*)(ws + 16777216);

    int nsplit = (ws_size >= (size_t)16777216 + 8 * 4259840) ? 8
               : (ws_size >= (size_t)16777216 + 4 * 4259840) ? 4
               : (ws_size >= (size_t)16777216 + 2 * 4259840) ? 2 : 1;
    float* lP = (float*)(ws + 16777216 + (size_t)nsplit * 4194304);

    prep_all<<<3072, 256, 0, stream>>>(x, xb, Wq, Wkv, Wout, WtQKV, WtOut);

    // [QK | Vt] = xb @ WtQKV^T; Q cols scaled by DH^-0.5*log2(e); V cols transposed
    gemm_bt<0, 2><<<dim3(32, 24), 256, 0, stream>>>(
        xb, WtQKV, nullptr, QK, Vt, 1024, 1024, 1024, 1024, 1024,
        0.18033688011112042f, 512);

    flash_attn<<<dim3(64, nsplit), 256, 0, stream>>>(QK, Vt, Ob, accP, lP,
                                                     16384 / nsplit, nsplit);
    if (nsplit > 1)
        merge_attn<<<1024, 256, 0, stream>>>(accP, lP, Ob, nsplit);

    // out = Ob @ WtOut^T + bout (fp32 out)
    gemm_bt<1, 2><<<dim3(32, 16), 256, 0, stream>>>(
        Ob, WtOut, bout, d_out, nullptr, 1 << 30, 512, 512, 512, 1024,
        1.0f, 0);
}